// Round 5
// baseline (131.469 us; speedup 1.0000x reference)
//
#include <hip/hip_runtime.h>
#include <hip/hip_bf16.h>

#define NROWS 4096
#define DIM   768
#define NKT   12          // 768 / 64 K-tiles (even)

typedef __attribute__((ext_vector_type(8))) short short8;
typedef __attribute__((ext_vector_type(4))) float f32x4;

#define GAS(p) ((const __attribute__((address_space(1))) void*)(p))
#define SAS(p) ((__attribute__((address_space(3))) void*)(p))

// fp32 -> bf16 round-to-nearest-even
__device__ __forceinline__ unsigned short f2bf(float x) {
    unsigned int u = __builtin_bit_cast(unsigned int, x);
    u += 0x7fffu + ((u >> 16) & 1u);
    return (unsigned short)(u >> 16);
}

// ---------------- Kernel 1: L2-normalize rows -> bf16; zero rowsum + counter ----------------
__global__ __launch_bounds__(256) void k_norm(const float* __restrict__ f1,
                                              const float* __restrict__ f2,
                                              unsigned short* __restrict__ n1,
                                              unsigned short* __restrict__ n2,
                                              float* __restrict__ rowsum,
                                              unsigned int* __restrict__ cnt) {
    int b = blockIdx.x;
    int wid = threadIdx.x >> 6, lane = threadIdx.x & 63;
    int rowidx = b * 4 + wid;                     // 0..8191, wave-uniform
    const float* src = (rowidx < NROWS) ? f1 : f2;
    unsigned short* dst = (rowidx < NROWS) ? n1 : n2;
    int row = rowidx & (NROWS - 1);
    const float4* srow = (const float4*)(src + (size_t)row * DIM);
    float4 v[3];
    float ss = 0.f;
#pragma unroll
    for (int r = 0; r < 3; ++r) {
        v[r] = srow[lane + 64 * r];
        ss += v[r].x * v[r].x + v[r].y * v[r].y + v[r].z * v[r].z + v[r].w * v[r].w;
    }
#pragma unroll
    for (int off = 32; off; off >>= 1) ss += __shfl_xor(ss, off);
    float inv = 1.0f / fmaxf(sqrtf(ss), 1e-8f);
    ushort4* drow = (ushort4*)(dst + (size_t)row * DIM);
#pragma unroll
    for (int r = 0; r < 3; ++r) {
        ushort4 o;
        o.x = f2bf(v[r].x * inv);
        o.y = f2bf(v[r].y * inv);
        o.z = f2bf(v[r].z * inv);
        o.w = f2bf(v[r].w * inv);
        drow[lane + 64 * r] = o;
    }
    if (b == 0) {                                  // zero rowsum (4096 f) + cnt
        float4 z = {0.f, 0.f, 0.f, 0.f};
#pragma unroll
        for (int i = 0; i < 4; ++i) ((float4*)rowsum)[threadIdx.x + 256 * i] = z;
        if (threadIdx.x == 0) *cnt = 0u;
    }
}

// ---------------- Kernel 2: 256x256-tile 8-phase bf16 MFMA GEMM + fused exp/row-sum + final ----------------
// 512 threads = 8 waves (2M x 4N), per-wave output 128x64. BK=64, dbuf LDS 128 KiB.
// T2 swizzle: within a 128 B row, byte_in_row ^= ((row&7)<<4); applied on the global SOURCE of
// global_load_lds (LDS dest linear) and on the ds_read address (both sides, same involution).

#define BARRIER __builtin_amdgcn_s_barrier()
#define WAIT_LGKM0 do { asm volatile("s_waitcnt lgkmcnt(0)" ::: "memory"); \
                        __builtin_amdgcn_sched_barrier(0); } while (0)
#define WAIT_VM4   do { asm volatile("s_waitcnt vmcnt(4)" ::: "memory"); \
                        __builtin_amdgcn_sched_barrier(0); } while (0)
#define WAIT_VM0   do { asm volatile("s_waitcnt vmcnt(0)" ::: "memory"); \
                        __builtin_amdgcn_sched_barrier(0); } while (0)
#define PRIO1 __builtin_amdgcn_s_setprio(1)
#define PRIO0 __builtin_amdgcn_s_setprio(0)

__global__ __launch_bounds__(512, 2) void k_gemm_lse(const unsigned short* __restrict__ n1,
                                                     const unsigned short* __restrict__ n2,
                                                     float* __restrict__ rowsum,
                                                     float* __restrict__ diag,
                                                     unsigned int* __restrict__ cnt,
                                                     float* __restrict__ out) {
    __shared__ alignas(16) char ldsbuf[131072];
    char* ldsc = (char*)ldsbuf;

    // XCD-aware bijective swizzle (256 % 8 == 0)
    int wg = blockIdx.x;
    int swz = (wg & 7) * 32 + (wg >> 3);
    int bi = swz >> 4;            // 16 i-tiles
    int bj = swz & 15;            // 16 j-tiles

    int tid = threadIdx.x;
    int wid = tid >> 6;
    int lane = tid & 63;
    int l15 = lane & 15, lk = lane >> 4;
    int wr = wid >> 2, wc = wid & 3;   // 2x4 wave grid

    const unsigned short* abase = n1 + (size_t)bi * 256 * DIM;
    const unsigned short* bbase = n2 + (size_t)bj * 256 * DIM;

    // staging: pre-swizzled global source, linear LDS dest (rule 21)
    const int stoff = (tid >> 3) * DIM + (((tid & 7) ^ ((tid >> 3) & 7)) * 8);

    // ds_read per-lane offsets: addr = regionbase + l15*128 + (k2 ^ ((lane&7)<<4))
    const int swzl = (lane & 7) << 4;
    const int lko0 = l15 * 128 + ((lk * 16) ^ swzl);          // kstep 0
    const int lko1 = l15 * 128 + (((64 + lk * 16)) ^ swzl);   // kstep 1

    char* LA[2];
    char* LB[2];
    LA[0] = ldsc + (0 * 4 + wr) * 16384;
    LA[1] = ldsc + (1 * 4 + wr) * 16384;
    LB[0] = ldsc + (0 * 4 + 2 + (wc >> 1)) * 16384 + (wc & 1) * (64 * 128);
    LB[1] = ldsc + (1 * 4 + 2 + (wc >> 1)) * 16384 + (wc & 1) * (64 * 128);

#define STG(b, slot, base, half, kt) do { \
    const unsigned short* _s = (base) + ((half) * 128) * DIM + (kt) * 64 + stoff; \
    char* _d = ldsc + ((b) * 4 + (slot)) * 16384 + wid * 1024; \
    __builtin_amdgcn_global_load_lds(GAS(_s), SAS(_d), 16, 0, 0); \
    __builtin_amdgcn_global_load_lds(GAS(_s + 64 * DIM), SAS(_d + 8192), 16, 0, 0); \
} while (0)

#define LDA_(b, qm) do { _Pragma("unroll") for (int m = 0; m < 4; ++m) { \
    const char* _p = LA[b] + ((qm) * 64 + m * 16) * 128; \
    a[m][0] = *(const short8*)(_p + lko0); \
    a[m][1] = *(const short8*)(_p + lko1); } } while (0)

#define LDB_(b, qn, breg) do { _Pragma("unroll") for (int n = 0; n < 2; ++n) { \
    const char* _p = LB[b] + ((qn) * 2 + n) * 16 * 128; \
    breg[n][0] = *(const short8*)(_p + lko0); \
    breg[n][1] = *(const short8*)(_p + lko1); } } while (0)

#define MM_(qm, qn, breg) do { _Pragma("unroll") for (int m = 0; m < 4; ++m) \
    _Pragma("unroll") for (int n = 0; n < 2; ++n) { \
    f32x4* _c = &acc[(qm) * 4 + m][(qn) * 2 + n]; \
    *_c = __builtin_amdgcn_mfma_f32_16x16x32_bf16(a[m][0], breg[n][0], *_c, 0, 0, 0); \
    *_c = __builtin_amdgcn_mfma_f32_16x16x32_bf16(a[m][1], breg[n][1], *_c, 0, 0, 0); } } while (0)

    short8 a[4][2], b0[2][2], b1[2][2];
    f32x4 acc[8][4] = {};

    // Prologue: tile0 all four halves + B halves of tile1. vmcnt(4) leaves {B0(1),B1(1)} in flight.
    STG(0, 0, abase, 0, 0); STG(0, 1, abase, 1, 0);
    STG(0, 2, bbase, 0, 0); STG(0, 3, bbase, 1, 0);
    STG(1, 2, bbase, 0, 1); STG(1, 3, bbase, 1, 1);
    WAIT_VM4;
    BARRIER;

    // main loop computes tiles t, t+1 for t = 0,2,...,NKT-4; tail peels the last pair.
    for (int t = 0; t + 3 < NKT; t += 2) {
        int t1 = t + 1, t2 = t + 2, t3 = t + 3;
        // ---- tile t from buf0 ----
        LDA_(0, 0); LDB_(0, 0, b0);
        STG(1, 0, abase, 0, t1);
        BARRIER; WAIT_LGKM0;
        PRIO1; MM_(0, 0, b0); PRIO0;
        BARRIER;
        LDB_(0, 1, b1);
        STG(1, 1, abase, 1, t1);
        BARRIER; WAIT_LGKM0;
        PRIO1; MM_(0, 1, b1); PRIO0;
        BARRIER;
        LDA_(0, 1);
        STG(0, 2, bbase, 0, t2);
        BARRIER; WAIT_LGKM0;
        PRIO1; MM_(1, 1, b1); PRIO0;
        BARRIER;
        STG(0, 3, bbase, 1, t2);
        BARRIER;
        PRIO1; MM_(1, 0, b0); PRIO0;
        WAIT_VM4;      // tile t+1 fully landed; {B0(t+2),B1(t+2)} stay in flight
        BARRIER;
        // ---- tile t+1 from buf1 ----
        LDA_(1, 0); LDB_(1, 0, b0);
        STG(0, 0, abase, 0, t2);
        BARRIER; WAIT_LGKM0;
        PRIO1; MM_(0, 0, b0); PRIO0;
        BARRIER;
        LDB_(1, 1, b1);
        STG(0, 1, abase, 1, t2);
        BARRIER; WAIT_LGKM0;
        PRIO1; MM_(0, 1, b1); PRIO0;
        BARRIER;
        LDA_(1, 1);
        STG(1, 2, bbase, 0, t3);
        BARRIER; WAIT_LGKM0;
        PRIO1; MM_(1, 1, b1); PRIO0;
        BARRIER;
        STG(1, 3, bbase, 1, t3);
        BARRIER;
        PRIO1; MM_(1, 0, b0); PRIO0;
        WAIT_VM4;      // tile t+2 fully landed; {B0(t+3),B1(t+3)} stay in flight
        BARRIER;
    }

    // ---- tail: tile NKT-2 from buf0 (stage only A(NKT-1)), then tile NKT-1 from buf1 ----
    {
        LDA_(0, 0); LDB_(0, 0, b0);
        STG(1, 0, abase, 0, NKT - 1);
        BARRIER; WAIT_LGKM0;
        PRIO1; MM_(0, 0, b0); PRIO0;
        BARRIER;
        LDB_(0, 1, b1);
        STG(1, 1, abase, 1, NKT - 1);
        BARRIER; WAIT_LGKM0;
        PRIO1; MM_(0, 1, b1); PRIO0;
        BARRIER;
        LDA_(0, 1);
        BARRIER; WAIT_LGKM0;
        PRIO1; MM_(1, 1, b1); PRIO0;
        BARRIER;
        PRIO1; MM_(1, 0, b0); PRIO0;
        WAIT_VM0;      // all of tile NKT-1 landed; nothing else in flight
        BARRIER;
        // tile NKT-1 from buf1, no staging
        LDA_(1, 0); LDB_(1, 0, b0);
        BARRIER; WAIT_LGKM0;
        PRIO1; MM_(0, 0, b0); PRIO0;
        BARRIER;
        LDB_(1, 1, b1);
        BARRIER; WAIT_LGKM0;
        PRIO1; MM_(0, 1, b1); PRIO0;
        BARRIER;
        LDA_(1, 1);
        BARRIER; WAIT_LGKM0;
        PRIO1; MM_(1, 1, b1); PRIO0;
        BARRIER;
        PRIO1; MM_(1, 0, b0); PRIO0;
        BARRIER;
    }

    // Epilogue. C/D layout: col = l15, row = lk*4 + r (per 16x16 frag).
    const bool dblk = (bi == bj);
    const int rowb = bi * 256 + wr * 128;
    const int colb = bj * 256 + wc * 64;
#pragma unroll
    for (int mi = 0; mi < 8; ++mi) {
#pragma unroll
        for (int r = 0; r < 4; ++r) {
            float s = 0.f;
            int gi = rowb + mi * 16 + lk * 4 + r;
#pragma unroll
            for (int ni = 0; ni < 4; ++ni) {
                float v = acc[mi][ni][r] * 20.0f;    // 1/TEMP
                s += __expf(v);
                if (dblk) {
                    int gj = colb + ni * 16 + l15;
                    if (gi == gj) diag[gi] = v;
                }
            }
#pragma unroll
            for (int off = 1; off < 16; off <<= 1) s += __shfl_xor(s, off);
            if (l15 == 0) atomicAdd(rowsum + gi, s);
        }
    }

    // ---- fused finalize: last block computes loss = mean(log(rowsum) - diag) ----
    __threadfence();                              // make diag stores + atomics agent-visible
    unsigned int* flag = (unsigned int*)ldsc;     // LDS reuse is safe: all ds ops barrier-drained
    if (tid == 0) {
        unsigned int old = __hip_atomic_fetch_add(cnt, 1u, __ATOMIC_ACQ_REL,
                                                  __HIP_MEMORY_SCOPE_AGENT);
        *flag = (old == 255u) ? 1u : 0u;
    }
    __syncthreads();
    if (*flag) {
        float s = 0.f;
#pragma unroll
        for (int k = 0; k < 8; ++k) {
            int idx = tid + 512 * k;
            float rs = __hip_atomic_load(rowsum + idx, __ATOMIC_RELAXED,
                                         __HIP_MEMORY_SCOPE_AGENT);
            float dg = __hip_atomic_load(diag + idx, __ATOMIC_RELAXED,
                                         __HIP_MEMORY_SCOPE_AGENT);
            s += logf(rs) - dg;
        }
#pragma unroll
        for (int off = 32; off; off >>= 1) s += __shfl_xor(s, off);
        float* red = (float*)(ldsc + 64);
        if (lane == 0) red[wid] = s;
        __syncthreads();
        if (tid == 0) {
            float tot = 0.f;
#pragma unroll
            for (int i = 0; i < 8; ++i) tot += red[i];
            out[0] = tot * (1.0f / NROWS);
        }
    }
}

extern "C" void kernel_launch(void* const* d_in, const int* in_sizes, int n_in,
                              void* d_out, int out_size, void* d_ws, size_t ws_size,
                              hipStream_t stream) {
    const float* f1 = (const float*)d_in[0];
    const float* f2 = (const float*)d_in[1];
    float* out = (float*)d_out;

    char* ws = (char*)d_ws;                       // layout: n1 | n2 | rowsum | diag | cnt
    unsigned short* n1 = (unsigned short*)ws;
    unsigned short* n2 = n1 + (size_t)NROWS * DIM;
    float* rowsum = (float*)(ws + 2 * (size_t)NROWS * DIM * sizeof(unsigned short));
    float* diag = rowsum + NROWS;
    unsigned int* cnt = (unsigned int*)(diag + NROWS);

    k_norm<<<2048, 256, 0, stream>>>(f1, f2, n1, n2, rowsum, cnt);
    k_gemm_lse<<<256, 512, 0, stream>>>(n1, n2, rowsum, diag, cnt, out);
}

// Round 6
// 106.258 us; speedup vs baseline: 1.2373x; 1.2373x over previous
//
#include <hip/hip_runtime.h>
#include <hip/hip_bf16.h>

#define NROWS 4096
#define DIM   768
#define NKT   12          // 768 / 64 K-tiles (even)

typedef __attribute__((ext_vector_type(8))) short short8;
typedef __attribute__((ext_vector_type(4))) float f32x4;

#define GAS(p) ((const __attribute__((address_space(1))) void*)(p))
#define SAS(p) ((__attribute__((address_space(3))) void*)(p))

// fp32 -> bf16 round-to-nearest-even
__device__ __forceinline__ unsigned short f2bf(float x) {
    unsigned int u = __builtin_bit_cast(unsigned int, x);
    u += 0x7fffu + ((u >> 16) & 1u);
    return (unsigned short)(u >> 16);
}

// ---------------- Kernel 1: L2-normalize rows -> bf16; also zero rowsum ----------------
__global__ __launch_bounds__(256) void k_norm(const float* __restrict__ f1,
                                              const float* __restrict__ f2,
                                              unsigned short* __restrict__ n1,
                                              unsigned short* __restrict__ n2,
                                              float* __restrict__ rowsum) {
    int b = blockIdx.x;
    int wid = threadIdx.x >> 6, lane = threadIdx.x & 63;
    int rowidx = b * 4 + wid;                     // 0..8191, wave-uniform
    const float* src = (rowidx < NROWS) ? f1 : f2;
    unsigned short* dst = (rowidx < NROWS) ? n1 : n2;
    int row = rowidx & (NROWS - 1);
    const float4* srow = (const float4*)(src + (size_t)row * DIM);
    float4 v[3];
    float ss = 0.f;
#pragma unroll
    for (int r = 0; r < 3; ++r) {
        v[r] = srow[lane + 64 * r];
        ss += v[r].x * v[r].x + v[r].y * v[r].y + v[r].z * v[r].z + v[r].w * v[r].w;
    }
#pragma unroll
    for (int off = 32; off; off >>= 1) ss += __shfl_xor(ss, off);
    float inv = 1.0f / fmaxf(sqrtf(ss), 1e-8f);
    ushort4* drow = (ushort4*)(dst + (size_t)row * DIM);
#pragma unroll
    for (int r = 0; r < 3; ++r) {
        ushort4 o;
        o.x = f2bf(v[r].x * inv);
        o.y = f2bf(v[r].y * inv);
        o.z = f2bf(v[r].z * inv);
        o.w = f2bf(v[r].w * inv);
        drow[lane + 64 * r] = o;
    }
    if (b == 0) {                                  // zero rowsum (4096 floats)
        float4 z = {0.f, 0.f, 0.f, 0.f};
#pragma unroll
        for (int i = 0; i < 4; ++i) ((float4*)rowsum)[threadIdx.x + 256 * i] = z;
    }
}

// ---------------- Kernel 2: 256x256-tile 8-phase bf16 MFMA GEMM + fused exp/row-sum ----------------
// R2 base (wrap-tail, separate finalize) + cross-phase fragment read-ahead:
// each phase's ds_reads are issued one phase EARLY (during the previous MFMA cluster),
// so the post-barrier lgkmcnt(0) finds them complete. Next-tile (A0,B0) reads issue
// right after WAIT_VM4 (buffer provably landed). Two A-fragment register sets (aA/aB).

#define BARRIER __builtin_amdgcn_s_barrier()
#define WAIT_LGKM0 do { asm volatile("s_waitcnt lgkmcnt(0)" ::: "memory"); \
                        __builtin_amdgcn_sched_barrier(0); } while (0)
#define WAIT_VM4   do { asm volatile("s_waitcnt vmcnt(4)" ::: "memory"); \
                        __builtin_amdgcn_sched_barrier(0); } while (0)
#define PRIO1 __builtin_amdgcn_s_setprio(1)
#define PRIO0 __builtin_amdgcn_s_setprio(0)

__global__ __launch_bounds__(512, 2) void k_gemm_lse(const unsigned short* __restrict__ n1,
                                                     const unsigned short* __restrict__ n2,
                                                     float* __restrict__ rowsum,
                                                     float* __restrict__ diag) {
    __shared__ alignas(16) char ldsbuf[131072];
    char* ldsc = (char*)ldsbuf;

    // XCD-aware bijective swizzle (256 % 8 == 0)
    int wg = blockIdx.x;
    int swz = (wg & 7) * 32 + (wg >> 3);
    int bi = swz >> 4;            // 16 i-tiles
    int bj = swz & 15;            // 16 j-tiles

    int tid = threadIdx.x;
    int wid = tid >> 6;
    int lane = tid & 63;
    int l15 = lane & 15, lk = lane >> 4;
    int wr = wid >> 2, wc = wid & 3;   // 2x4 wave grid

    const unsigned short* abase = n1 + (size_t)bi * 256 * DIM;
    const unsigned short* bbase = n2 + (size_t)bj * 256 * DIM;

    // staging: pre-swizzled global source, linear LDS dest (rule 21)
    const int stoff = (tid >> 3) * DIM + (((tid & 7) ^ ((tid >> 3) & 7)) * 8);

    // ds_read per-lane offsets: addr = regionbase + l15*128 + (k2 ^ ((lane&7)<<4))
    const int swzl = (lane & 7) << 4;
    const int lko0 = l15 * 128 + ((lk * 16) ^ swzl);          // kstep 0
    const int lko1 = l15 * 128 + (((64 + lk * 16)) ^ swzl);   // kstep 1

    char* LA[2];
    char* LB[2];
    LA[0] = ldsc + (0 * 4 + wr) * 16384;
    LA[1] = ldsc + (1 * 4 + wr) * 16384;
    LB[0] = ldsc + (0 * 4 + 2 + (wc >> 1)) * 16384 + (wc & 1) * (64 * 128);
    LB[1] = ldsc + (1 * 4 + 2 + (wc >> 1)) * 16384 + (wc & 1) * (64 * 128);

#define STG(b, slot, base, half, kt) do { \
    const unsigned short* _s = (base) + ((half) * 128) * DIM + (kt) * 64 + stoff; \
    char* _d = ldsc + ((b) * 4 + (slot)) * 16384 + wid * 1024; \
    __builtin_amdgcn_global_load_lds(GAS(_s), SAS(_d), 16, 0, 0); \
    __builtin_amdgcn_global_load_lds(GAS(_s + 64 * DIM), SAS(_d + 8192), 16, 0, 0); \
} while (0)

#define LDA_(b, qm, areg) do { _Pragma("unroll") for (int m = 0; m < 4; ++m) { \
    const char* _p = LA[b] + ((qm) * 64 + m * 16) * 128; \
    areg[m][0] = *(const short8*)(_p + lko0); \
    areg[m][1] = *(const short8*)(_p + lko1); } } while (0)

#define LDB_(b, qn, breg) do { _Pragma("unroll") for (int n = 0; n < 2; ++n) { \
    const char* _p = LB[b] + ((qn) * 2 + n) * 16 * 128; \
    breg[n][0] = *(const short8*)(_p + lko0); \
    breg[n][1] = *(const short8*)(_p + lko1); } } while (0)

#define MM_(qm, qn, areg, breg) do { _Pragma("unroll") for (int m = 0; m < 4; ++m) \
    _Pragma("unroll") for (int n = 0; n < 2; ++n) { \
    f32x4* _c = &acc[(qm) * 4 + m][(qn) * 2 + n]; \
    *_c = __builtin_amdgcn_mfma_f32_16x16x32_bf16(areg[m][0], breg[n][0], *_c, 0, 0, 0); \
    *_c = __builtin_amdgcn_mfma_f32_16x16x32_bf16(areg[m][1], breg[n][1], *_c, 0, 0, 0); } } while (0)

    short8 aA[4][2], aB[4][2], b0[2][2], b1[2][2];
    f32x4 acc[8][4] = {};

    // Prologue: tile0 all four halves + B halves of tile1. vmcnt(4) leaves {B0(1),B1(1)} in flight.
    STG(0, 0, abase, 0, 0); STG(0, 1, abase, 1, 0);
    STG(0, 2, bbase, 0, 0); STG(0, 3, bbase, 1, 0);
    STG(1, 2, bbase, 0, 1); STG(1, 3, bbase, 1, 1);
    WAIT_VM4;
    BARRIER;
    LDA_(0, 0, aA); LDB_(0, 0, b0);    // read-ahead for ph0

    for (int t = 0; t < NKT; t += 2) {
        int t1 = t + 1;
        int t2 = (t + 2 < NKT) ? t + 2 : t + 2 - NKT;   // wrap: staged-but-never-read on last iter
        int t3 = (t + 3 < NKT) ? t + 3 : t + 3 - NKT;
        // ---- tile t from buf0 ----
        // ph0: consume {aA,b0}; issue b1
        STG(1, 0, abase, 0, t1);
        BARRIER; WAIT_LGKM0;
        LDB_(0, 1, b1);
        PRIO1; MM_(0, 0, aA, b0); PRIO0;
        BARRIER;
        // ph1: consume {aA,b1}; issue aB
        STG(1, 1, abase, 1, t1);
        BARRIER; WAIT_LGKM0;
        LDA_(0, 1, aB);
        PRIO1; MM_(0, 1, aA, b1); PRIO0;
        BARRIER;
        // ph2: consume {aB,b1}
        STG(0, 2, bbase, 0, t2);
        BARRIER; WAIT_LGKM0;
        PRIO1; MM_(1, 1, aB, b1); PRIO0;
        BARRIER;
        // ph3: consume {aB,b0} (all in regs); after VM4 buf1 is landed -> read-ahead next tile
        STG(0, 3, bbase, 1, t2);
        BARRIER;
        PRIO1; MM_(1, 0, aB, b0); PRIO0;
        WAIT_VM4;      // tile t+1 fully landed; {B0(t+2),B1(t+2)} stay in flight
        LDA_(1, 0, aA); LDB_(1, 0, b0);
        BARRIER;
        // ---- tile t+1 from buf1 ----
        // ph4
        STG(0, 0, abase, 0, t2);
        BARRIER; WAIT_LGKM0;
        LDB_(1, 1, b1);
        PRIO1; MM_(0, 0, aA, b0); PRIO0;
        BARRIER;
        // ph5
        STG(0, 1, abase, 1, t2);
        BARRIER; WAIT_LGKM0;
        LDA_(1, 1, aB);
        PRIO1; MM_(0, 1, aA, b1); PRIO0;
        BARRIER;
        // ph6
        STG(1, 2, bbase, 0, t3);
        BARRIER; WAIT_LGKM0;
        PRIO1; MM_(1, 1, aB, b1); PRIO0;
        BARRIER;
        // ph7
        STG(1, 3, bbase, 1, t3);
        BARRIER;
        PRIO1; MM_(1, 0, aB, b0); PRIO0;
        WAIT_VM4;      // tile t+2 fully landed; {B0(t+3),B1(t+3)} stay in flight
        LDA_(0, 0, aA); LDB_(0, 0, b0);   // dead on last iteration (wrapped data, valid LDS)
        BARRIER;
    }

    __syncthreads();   // drains remaining vmcnt/lgkmcnt before epilogue

    // Epilogue. C/D layout: col = l15, row = lk*4 + r (per 16x16 frag).
    const bool dblk = (bi == bj);
    const int rowb = bi * 256 + wr * 128;
    const int colb = bj * 256 + wc * 64;
#pragma unroll
    for (int mi = 0; mi < 8; ++mi) {
#pragma unroll
        for (int r = 0; r < 4; ++r) {
            float s = 0.f;
            int gi = rowb + mi * 16 + lk * 4 + r;
#pragma unroll
            for (int ni = 0; ni < 4; ++ni) {
                float v = acc[mi][ni][r] * 20.0f;    // 1/TEMP
                s += __expf(v);
                if (dblk) {
                    int gj = colb + ni * 16 + l15;
                    if (gi == gj) diag[gi] = v;
                }
            }
#pragma unroll
            for (int off = 1; off < 16; off <<= 1) s += __shfl_xor(s, off);
            if (l15 == 0) atomicAdd(rowsum + gi, s);
        }
    }
}

// ---------------- Kernel 3: loss = mean(log(rowsum) - diag) ----------------
__global__ __launch_bounds__(1024) void k_final(const float* __restrict__ rowsum,
                                                const float* __restrict__ diag,
                                                float* __restrict__ out) {
    int tid = threadIdx.x;
    float s = 0.f;
#pragma unroll
    for (int i = 0; i < 4; ++i) {
        int idx = tid + 1024 * i;
        s += logf(rowsum[idx]) - diag[idx];
    }
#pragma unroll
    for (int off = 32; off; off >>= 1) s += __shfl_xor(s, off);
    __shared__ float red[16];
    if ((tid & 63) == 0) red[tid >> 6] = s;
    __syncthreads();
    if (tid == 0) {
        float tot = 0.f;
#pragma unroll
        for (int i = 0; i < 16; ++i) tot += red[i];
        out[0] = tot * (1.0f / NROWS);
    }
}

extern "C" void kernel_launch(void* const* d_in, const int* in_sizes, int n_in,
                              void* d_out, int out_size, void* d_ws, size_t ws_size,
                              hipStream_t stream) {
    const float* f1 = (const float*)d_in[0];
    const float* f2 = (const float*)d_in[1];
    float* out = (float*)d_out;

    char* ws = (char*)d_ws;                       // layout: n1 | n2 | rowsum | diag
    unsigned short* n1 = (unsigned short*)ws;
    unsigned short* n2 = n1 + (size_t)NROWS * DIM;
    float* rowsum = (float*)(ws + 2 * (size_t)NROWS * DIM * sizeof(unsigned short));
    float* diag = rowsum + NROWS;

    k_norm<<<2048, 256, 0, stream>>>(f1, f2, n1, n2, rowsum);
    k_gemm_lse<<<256, 512, 0, stream>>>(n1, n2, rowsum, diag);
    k_final<<<1, 1024, 0, stream>>>(rowsum, diag, out);
}